// Round 1
// baseline (2062.466 us; speedup 1.0000x reference)
//
#include <hip/hip_runtime.h>

// Ocean advection + 3x3 binomial smoothing, 48 steps, fp32.
// Inputs: T(B,H,W), ug(B,H,W), vg(B,H,W), lat(H), lon(W), mask(H,W)
// One fused kernel per step: LDS tile with halo-2 of T -> Tmid (halo-1, zero
// outside domain = conv zero-pad) -> 3x3 binomial conv * mask -> Tout.

#define DEG2RAD 0.017453292519943295f
#define R_EARTH 6371000.0f
#define DT_S 600.0f

constexpr int TW = 64;            // output tile width  (W axis)
constexpr int TH = 32;            // output tile height (H axis)
constexpr int STW = TW + 4;       // 68: T tile cols (halo 2)
constexpr int STH = TH + 4;       // 36: T tile rows
constexpr int MTW = TW + 2;       // 66: Tmid tile cols (halo 1)
constexpr int MTH = TH + 2;       // 34: Tmid tile rows
constexpr int NT  = 256;          // threads per block

__global__ __launch_bounds__(256)
void prep_kernel(const float* __restrict__ lat, const float* __restrict__ lon,
                 float* __restrict__ coef, int H) {
    int h = blockIdx.x * blockDim.x + threadIdx.x;
    if (h < H) {
        float dlon = lon[1] - lon[0];
        coef[h] = 1.0f / (R_EARTH * DEG2RAD * dlon * cosf(lat[h] * DEG2RAD));
    }
    if (h == 0) {
        float dlat = lat[1] - lat[0];
        coef[H] = 1.0f / (R_EARTH * DEG2RAD * dlat);
    }
}

__global__ __launch_bounds__(256)
void step_kernel(const float* __restrict__ Tin, const float* __restrict__ ug,
                 const float* __restrict__ vg, const float* __restrict__ mask,
                 const float* __restrict__ coef, float* __restrict__ Tout,
                 int H, int W) {
    __shared__ float sT[STH][STW];
    __shared__ float sM[MTH][MTW];

    const int tid = threadIdx.x;
    const int w0 = blockIdx.x * TW;
    const int h0 = blockIdx.y * TH;
    const int b  = blockIdx.z;
    const long plane = (long)H * W;
    const float* __restrict__ Tb  = Tin + b * plane;
    const float* __restrict__ ugb = ug  + b * plane;
    const float* __restrict__ vgb = vg  + b * plane;
    const float inv_dy = coef[H];

    // 1) Stage T tile with clamped halo-2.
    for (int i = tid; i < STH * STW; i += NT) {
        int r = i / STW, c = i - r * STW;
        int gh = h0 - 2 + r; gh = min(max(gh, 0), H - 1);
        int gw = w0 - 2 + c; gw = min(max(gw, 0), W - 1);
        sT[r][c] = Tb[gh * W + gw];
    }
    __syncthreads();

    // 2) Tmid = T + DT * F over tile + halo-1; zero outside domain (conv pad).
    for (int i = tid; i < MTH * MTW; i += NT) {
        int r = i / MTW, c = i - r * MTW;
        int gh = h0 - 1 + r;
        int gw = w0 - 1 + c;
        float v = 0.0f;
        if (gh >= 0 && gh < H && gw >= 0 && gw < W) {
            int sr = r + 1, sc = c + 1;
            float tC  = sT[sr][sc];
            float ndy = sT[sr + 1][sc] - sT[sr - 1][sc]; // clamped halo => correct
            float ndx = sT[sr][sc + 1] - sT[sr][sc - 1]; // one-sided numerators at edges
            float sy  = (gh == 0 || gh == H - 1) ? inv_dy : 0.5f * inv_dy;
            float ix  = coef[gh];
            float sx  = (gw == 0 || gw == W - 1) ? ix : 0.5f * ix;
            int   gi  = gh * W + gw;
            float m   = mask[gi];
            float F   = -(ugb[gi] * (ndx * sx) + vgb[gi] * (ndy * sy)) * m;
            v = tC + DT_S * F;
        }
        sM[r][c] = v;
    }
    __syncthreads();

    // 3) 3x3 binomial conv (zero pad via sM zeros) * mask -> Tout.
    float* __restrict__ To = Tout + b * plane;
    for (int i = tid; i < TH * TW; i += NT) {
        int r = i >> 6, c = i & (TW - 1);   // TW = 64
        int gh = h0 + r, gw = w0 + c;
        if (gh < H && gw < W) {
            int sr = r + 1, sc = c + 1;
            float s =        (sM[sr-1][sc-1] + sM[sr-1][sc+1] + sM[sr+1][sc-1] + sM[sr+1][sc+1])
                    + 2.0f * (sM[sr-1][sc  ] + sM[sr+1][sc  ] + sM[sr  ][sc-1] + sM[sr  ][sc+1])
                    + 4.0f *  sM[sr][sc];
            To[gh * W + gw] = s * (1.0f / 16.0f) * mask[gh * W + gw];
        }
    }
}

extern "C" void kernel_launch(void* const* d_in, const int* in_sizes, int n_in,
                              void* d_out, int out_size, void* d_ws, size_t ws_size,
                              hipStream_t stream) {
    const float* T0   = (const float*)d_in[0];
    const float* ug   = (const float*)d_in[1];
    const float* vg   = (const float*)d_in[2];
    const float* lat  = (const float*)d_in[3];
    const float* lon  = (const float*)d_in[4];
    const float* mask = (const float*)d_in[5];

    const int H = in_sizes[3];
    const int W = in_sizes[4];
    const int B = in_sizes[0] / (H * W);

    float* out  = (float*)d_out;
    float* ping = (float*)d_ws;                         // B*H*W floats
    float* coef = ping + (size_t)B * H * W;             // H+1 floats (1/dx[h], then 1/dy)

    prep_kernel<<<dim3((H + NT - 1) / NT), dim3(NT), 0, stream>>>(lat, lon, coef, H);

    dim3 grid((W + TW - 1) / TW, (H + TH - 1) / TH, B);
    const int STEPS = 48;
    for (int i = 0; i < STEPS; ++i) {
        const float* src = (i == 0) ? T0 : ((i & 1) ? ping : out);
        float*       dst = (i & 1) ? out : ping;
        step_kernel<<<grid, dim3(NT), 0, stream>>>(src, ug, vg, mask, coef, dst, H, W);
    }
}